// Round 1
// baseline (139.148 us; speedup 1.0000x reference)
//
#include <hip/hip_runtime.h>
#include <hip/hip_bf16.h>

// ---- types ----
typedef __attribute__((ext_vector_type(8))) short bf16x8;   // 8 bf16 in 4 VGPRs (MFMA A/B frag)
typedef __attribute__((ext_vector_type(4))) float f32x4;    // MFMA C/D frag
typedef __attribute__((ext_vector_type(4))) short s16x4;

#define DM 512
#define T_SEQ 512
#define NSEQ 32         // B*S = 2*16
#define MROWS 16384     // NSEQ * T_SEQ
#define QKV_DIM 768
#define HD 64
#define NEG_INF_F (-1000000000.0f)

// f32 -> bf16 bits, round-to-nearest-even
__device__ __forceinline__ short f2bf(float f) {
    unsigned int u = __builtin_bit_cast(unsigned int, f);
    unsigned int r = (u + 0x7FFFu + ((u >> 16) & 1u)) >> 16;
    return (short)r;
}

__device__ __forceinline__ void gload16(const void* g, void* l) {
    __builtin_amdgcn_global_load_lds(
        (const __attribute__((address_space(1))) void*)g,
        (__attribute__((address_space(3))) void*)l, 16, 0, 0);
}

// ---------------- kernel 0: converts + rope table ----------------
// blocks [0,16384): xt rows; [16384,17664): weight rows; [17664,17792): rope table
__global__ __launch_bounds__(128) void k_convert(
    const float* __restrict__ x, const float* __restrict__ qkvw, const float* __restrict__ owf,
    short* __restrict__ xt, short* __restrict__ qw, short* __restrict__ ow,
    float* __restrict__ cosT, float* __restrict__ sinT)
{
    int bidx = blockIdx.x, tid = threadIdx.x;
    if (bidx < MROWS) {
        int m = bidx; int n = m >> 9, t = m & 511, b = n >> 4, s = n & 15;
        const float* src = x + ((size_t)((b * 512 + t) * 16 + s)) * 512;
        float4 v = *(const float4*)(src + tid * 4);
        s16x4 o; o.x = f2bf(v.x); o.y = f2bf(v.y); o.z = f2bf(v.z); o.w = f2bf(v.w);
        *(s16x4*)(xt + (size_t)m * 512 + tid * 4) = o;
    } else if (bidx < MROWS + 1280) {
        int wr = bidx - MROWS;
        const float* src; short* dst;
        if (wr < QKV_DIM) { src = qkvw + (size_t)wr * 512; dst = qw + (size_t)wr * 512; }
        else             { src = owf + (size_t)(wr - QKV_DIM) * 512; dst = ow + (size_t)(wr - QKV_DIM) * 512; }
        float4 v = *(const float4*)(src + tid * 4);
        s16x4 o; o.x = f2bf(v.x); o.y = f2bf(v.y); o.z = f2bf(v.z); o.w = f2bf(v.w);
        *(s16x4*)(dst + tid * 4) = o;
    } else {
        int idx = (bidx - (MROWS + 1280)) * 128 + tid;   // 0..16383 = t*32+d
        int t = idx >> 5, d = idx & 31;
        float inv = powf(10000.0f, -(float)d * (1.0f / 32.0f));
        float ang = (float)t * inv;
        float sv, cv; sincosf(ang, &sv, &cv);
        cosT[idx] = cv; sinT[idx] = sv;
    }
}

// ---------------- shared GEMM mainloop: 128x128 tile, BK=32, 4 waves ----------------
// A,B both row-major with K contiguous (B is W so C = A @ W^T). acc[mf][nf]:
// C row = bm*128 + wr + mf*16 + (lane>>4)*4 + reg ; col = bn*128 + wc + nf*16 + (lane&15)
__device__ __forceinline__ void gemm_mainloop(
    const short* __restrict__ Ab, const short* __restrict__ Bb, int K,
    short* As, short* Bs, int wave, int lane, f32x4 acc[4][4])
{
    int wr = (wave >> 1) * 64, wc = (wave & 1) * 64;
    for (int kt = 0; kt < K; kt += 32) {
        __syncthreads();
        #pragma unroll
        for (int c = 0; c < 2; ++c) {
            int chunk = (wave * 2 + c) * 64 + lane;
            int row = chunk >> 2, kc = chunk & 3;
            gload16(Ab + (size_t)row * K + kt + kc * 8, As + (wave * 2 + c) * 512);
            gload16(Bb + (size_t)row * K + kt + kc * 8, Bs + (wave * 2 + c) * 512);
        }
        __syncthreads();
        bf16x8 af[4], bg[4];
        #pragma unroll
        for (int mf = 0; mf < 4; ++mf)
            af[mf] = *(const bf16x8*)(As + (wr + mf * 16 + (lane & 15)) * 32 + ((lane >> 4) << 3));
        #pragma unroll
        for (int nf = 0; nf < 4; ++nf)
            bg[nf] = *(const bf16x8*)(Bs + (wc + nf * 16 + (lane & 15)) * 32 + ((lane >> 4) << 3));
        #pragma unroll
        for (int mf = 0; mf < 4; ++mf)
            #pragma unroll
            for (int nf = 0; nf < 4; ++nf)
                acc[mf][nf] = __builtin_amdgcn_mfma_f32_16x16x32_bf16(af[mf], bg[nf], acc[mf][nf], 0, 0, 0);
    }
}

// ---------------- kernel 1: QKV GEMM + fused RoPE epilogue ----------------
// grid (128, 6). Each wave owns a 64-col group == exactly one head-sized chunk.
__global__ __launch_bounds__(256) void k_gemm_qkv(
    const short* __restrict__ xt, const short* __restrict__ qw,
    const float* __restrict__ cosT, const float* __restrict__ sinT,
    short* __restrict__ qb, short* __restrict__ kb, short* __restrict__ vb)
{
    __shared__ short As[128 * 32], Bs[128 * 32];
    int tid = threadIdx.x, wave = tid >> 6, lane = tid & 63;
    int bm = blockIdx.x, bn = blockIdx.y;
    f32x4 acc[4][4] = {};
    gemm_mainloop(xt + (size_t)bm * 128 * 512, qw + (size_t)bn * 128 * 512, 512, As, Bs, wave, lane, acc);

    int wr = (wave >> 1) * 64, wc = (wave & 1) * 64;
    int gbase = bn * 128 + wc;        // 64-aligned absolute col base of this wave
    int cl = lane & 15;
    #pragma unroll
    for (int mf = 0; mf < 4; ++mf) {
        #pragma unroll
        for (int rg = 0; rg < 4; ++rg) {
            int r = bm * 128 + wr + mf * 16 + ((lane >> 4) << 2) + rg;
            int n = r >> 9, t = r & 511;
            #pragma unroll
            for (int nf = 0; nf < 2; ++nf) {
                int dlo = nf * 16 + cl;              // [0,32)
                float v1 = acc[mf][nf][rg];
                float v2 = acc[mf][nf + 2][rg];
                if (gbase < 512) {                   // q: rope + 0.125 pre-scale
                    int h = gbase >> 6;
                    float c = cosT[t * 32 + dlo], s = sinT[t * 32 + dlo];
                    size_t base = ((size_t)(n * 8 + h) * 512 + t) * 64;
                    qb[base + dlo]      = f2bf((v1 * c - v2 * s) * 0.125f);
                    qb[base + dlo + 32] = f2bf((v1 * s + v2 * c) * 0.125f);
                } else if (gbase < 640) {            // k: rope
                    int g = (gbase - 512) >> 6;
                    float c = cosT[t * 32 + dlo], s = sinT[t * 32 + dlo];
                    size_t base = ((size_t)(n * 2 + g) * 512 + t) * 64;
                    kb[base + dlo]      = f2bf(v1 * c - v2 * s);
                    kb[base + dlo + 32] = f2bf(v1 * s + v2 * c);
                } else {                             // v: passthrough
                    int g = (gbase - 640) >> 6;
                    size_t base = ((size_t)(n * 2 + g) * 512 + t) * 64;
                    vb[base + dlo]      = f2bf(v1);
                    vb[base + dlo + 32] = f2bf(v2);
                }
            }
        }
    }
}

// ---------------- kernel 2: causal GQA flash attention ----------------
// grid 1024 = n(32) x h(8) x qt(4). Block: 4 waves, wave w owns q rows [qt*128+w*32, +32).
__global__ __launch_bounds__(256) void k_attn(
    const short* __restrict__ qb, const short* __restrict__ kb, const short* __restrict__ vb,
    const int* __restrict__ pm, short* __restrict__ ao)
{
    __shared__ short Kt[64 * 64];        // XOR-swizzled row-major [kv][d]
    __shared__ short Vt[64 * 72];        // transposed [d][kv], pad 72 (row=144B, 16B aligned)
    __shared__ short Pw[4][32 * 72];     // per-wave P, pad 72
    int tid = threadIdx.x, wave = tid >> 6, lane = tid & 63;
    int bid = blockIdx.x;
    int qt = bid & 3, h = (bid >> 2) & 7, n = bid >> 5;
    int g = h >> 2;
    int q0 = qt * 128 + wave * 32;
    const short* Qb = qb + ((size_t)(n * 8 + h) * 512) * 64;
    const short* Kb = kb + ((size_t)(n * 2 + g) * 512) * 64;
    const short* Vb = vb + ((size_t)(n * 2 + g) * 512) * 64;

    bf16x8 qf[2][2];
    #pragma unroll
    for (int mf = 0; mf < 2; ++mf)
        #pragma unroll
        for (int ks = 0; ks < 2; ++ks)
            qf[mf][ks] = *(const bf16x8*)(Qb + (size_t)(q0 + mf * 16 + (lane & 15)) * 64 + ks * 32 + ((lane >> 4) << 3));

    f32x4 Oc[2][4] = {};
    float mrow[2][4], lrow[2][4];
    bool rvalid[2][4];
    #pragma unroll
    for (int mf = 0; mf < 2; ++mf)
        #pragma unroll
        for (int rg = 0; rg < 4; ++rg) {
            mrow[mf][rg] = -1e30f; lrow[mf][rg] = 0.f;
            int r = q0 + mf * 16 + ((lane >> 4) << 2) + rg;
            rvalid[mf][rg] = pm[n * 512 + r] != 0;
        }

    int ntiles = (qt + 1) * 2;
    for (int jt = 0; jt < ntiles; ++jt) {
        int c0 = jt * 64;
        __syncthreads();
        // stage K with XOR swizzle (512 x 16B chunks)
        #pragma unroll
        for (int cc = 0; cc < 2; ++cc) {
            int sidx = tid + cc * 256;
            int row = sidx >> 3, kc = sidx & 7;
            uint4 d = *(const uint4*)(Kb + (size_t)(c0 + row) * 64 + kc * 8);
            *(uint4*)(Kt + row * 64 + ((kc ^ (row & 7)) << 3)) = d;
        }
        // stage V transposed: thread covers 16 d at one kv
        {
            int kv = tid >> 2, part = tid & 3;
            const short* vsrc = Vb + (size_t)(c0 + kv) * 64 + part * 16;
            uint4 a  = *(const uint4*)(vsrc);
            uint4 b2 = *(const uint4*)(vsrc + 8);
            const short* pa = (const short*)&a;
            const short* pb = (const short*)&b2;
            #pragma unroll
            for (int j = 0; j < 8; ++j) Vt[(part * 16 + j) * 72 + kv] = pa[j];
            #pragma unroll
            for (int j = 0; j < 8; ++j) Vt[(part * 16 + 8 + j) * 72 + kv] = pb[j];
        }
        __syncthreads();
        if (c0 <= q0 + 31) {
            // S = Q K^T  (Q pre-scaled by 0.125)
            f32x4 sacc[2][4] = {};
            #pragma unroll
            for (int ks = 0; ks < 2; ++ks) {
                bf16x8 kf[4];
                #pragma unroll
                for (int nf = 0; nf < 4; ++nf) {
                    int row = nf * 16 + (lane & 15);
                    int kc = ks * 4 + (lane >> 4);
                    kf[nf] = *(const bf16x8*)(Kt + row * 64 + ((kc ^ (row & 7)) << 3));
                }
                #pragma unroll
                for (int mf = 0; mf < 2; ++mf)
                    #pragma unroll
                    for (int nf = 0; nf < 4; ++nf)
                        sacc[mf][nf] = __builtin_amdgcn_mfma_f32_16x16x32_bf16(qf[mf][ks], kf[nf], sacc[mf][nf], 0, 0, 0);
            }
            // mask + online softmax
            #pragma unroll
            for (int mf = 0; mf < 2; ++mf) {
                #pragma unroll
                for (int rg = 0; rg < 4; ++rg) {
                    int r = q0 + mf * 16 + ((lane >> 4) << 2) + rg;
                    float rmax = -1e30f;
                    #pragma unroll
                    for (int nf = 0; nf < 4; ++nf) {
                        int ccol = c0 + nf * 16 + (lane & 15);
                        float sv = sacc[mf][nf][rg];
                        sv = (ccol <= r && rvalid[mf][rg]) ? sv : NEG_INF_F;
                        sacc[mf][nf][rg] = sv;
                        rmax = fmaxf(rmax, sv);
                    }
                    #pragma unroll
                    for (int off = 1; off < 16; off <<= 1) rmax = fmaxf(rmax, __shfl_xor(rmax, off));
                    float mold = mrow[mf][rg];
                    float mnew = fmaxf(mold, rmax);
                    float alpha = __expf(mold - mnew);
                    mrow[mf][rg] = mnew;
                    float rsum = 0.f;
                    #pragma unroll
                    for (int nf = 0; nf < 4; ++nf) {
                        float p = __expf(sacc[mf][nf][rg] - mnew);
                        sacc[mf][nf][rg] = p;
                        rsum += p;
                    }
                    #pragma unroll
                    for (int off = 1; off < 16; off <<= 1) rsum += __shfl_xor(rsum, off);
                    lrow[mf][rg] = lrow[mf][rg] * alpha + rsum;
                    #pragma unroll
                    for (int nf = 0; nf < 4; ++nf) Oc[mf][nf][rg] *= alpha;
                }
            }
            // P -> LDS (bf16)
            short* Pme = Pw[wave];
            #pragma unroll
            for (int mf = 0; mf < 2; ++mf)
                #pragma unroll
                for (int nf = 0; nf < 4; ++nf)
                    #pragma unroll
                    for (int rg = 0; rg < 4; ++rg) {
                        int prow = mf * 16 + ((lane >> 4) << 2) + rg;
                        Pme[prow * 72 + nf * 16 + (lane & 15)] = f2bf(sacc[mf][nf][rg]);
                    }
            // O += P V
            #pragma unroll
            for (int ks = 0; ks < 2; ++ks) {
                bf16x8 pf[2], vf[4];
                #pragma unroll
                for (int mf = 0; mf < 2; ++mf)
                    pf[mf] = *(const bf16x8*)(Pme + (mf * 16 + (lane & 15)) * 72 + ks * 32 + ((lane >> 4) << 3));
                #pragma unroll
                for (int nf = 0; nf < 4; ++nf)
                    vf[nf] = *(const bf16x8*)(Vt + (nf * 16 + (lane & 15)) * 72 + ks * 32 + ((lane >> 4) << 3));
                #pragma unroll
                for (int mf = 0; mf < 2; ++mf)
                    #pragma unroll
                    for (int nf = 0; nf < 4; ++nf)
                        Oc[mf][nf] = __builtin_amdgcn_mfma_f32_16x16x32_bf16(pf[mf], vf[nf], Oc[mf][nf], 0, 0, 0);
            }
        }
    }
    // epilogue: O /= l, write [m=(n,t)][h*64+d] bf16
    #pragma unroll
    for (int mf = 0; mf < 2; ++mf)
        #pragma unroll
        for (int rg = 0; rg < 4; ++rg) {
            int r = q0 + mf * 16 + ((lane >> 4) << 2) + rg;
            float inv = 1.0f / lrow[mf][rg];
            size_t base = ((size_t)n * 512 + r) * 512 + h * 64;
            #pragma unroll
            for (int nf = 0; nf < 4; ++nf)
                ao[base + nf * 16 + (lane & 15)] = f2bf(Oc[mf][nf][rg] * inv);
        }
}

// ---------------- kernel 3: output projection + (B,T,S,D) scatter ----------------
__global__ __launch_bounds__(256) void k_gemm_out(
    const short* __restrict__ ao, const short* __restrict__ ow, float* __restrict__ out)
{
    __shared__ short As[128 * 32], Bs[128 * 32];
    int tid = threadIdx.x, wave = tid >> 6, lane = tid & 63;
    int bm = blockIdx.x, bn = blockIdx.y;
    f32x4 acc[4][4] = {};
    gemm_mainloop(ao + (size_t)bm * 128 * 512, ow + (size_t)bn * 128 * 512, 512, As, Bs, wave, lane, acc);

    int wr = (wave >> 1) * 64, wc = (wave & 1) * 64;
    #pragma unroll
    for (int mf = 0; mf < 4; ++mf) {
        #pragma unroll
        for (int rg = 0; rg < 4; ++rg) {
            int r = bm * 128 + wr + mf * 16 + ((lane >> 4) << 2) + rg;
            int n = r >> 9, t = r & 511, b = n >> 4, s = n & 15;
            size_t obase = ((size_t)((b * 512 + t) * 16 + s)) * 512;
            #pragma unroll
            for (int nf = 0; nf < 4; ++nf) {
                int c = bn * 128 + wc + nf * 16 + (lane & 15);
                out[obase + c] = acc[mf][nf][rg];
            }
        }
    }
}

// ---------------- launch ----------------
extern "C" void kernel_launch(void* const* d_in, const int* in_sizes, int n_in,
                              void* d_out, int out_size, void* d_ws, size_t ws_size,
                              hipStream_t stream) {
    (void)in_sizes; (void)n_in; (void)out_size; (void)ws_size;
    const float* x    = (const float*)d_in[0];
    const int*   pmsk = (const int*)d_in[1];
    const float* qkvw = (const float*)d_in[2];
    const float* owf  = (const float*)d_in[3];
    char* ws = (char*)d_ws;
    short* xt   = (short*)(ws + 0);          // 16,777,216 B (reused as attn-out)
    short* qw   = (short*)(ws + 16777216);   //    786,432 B
    short* ow   = (short*)(ws + 17563648);   //    524,288 B
    float* cosT = (float*)(ws + 18087936);   //     65,536 B
    float* sinT = (float*)(ws + 18153472);   //     65,536 B
    short* qbuf = (short*)(ws + 18219008);   // 16,777,216 B
    short* kbuf = (short*)(ws + 34996224);   //  4,194,304 B
    short* vbuf = (short*)(ws + 39190528);   //  4,194,304 B  (end 43,384,832)
    short* aobuf = xt;                       // xt dead after GEMM1 -> reuse
    float* out = (float*)d_out;

    k_convert<<<dim3(17792), dim3(128), 0, stream>>>(x, qkvw, owf, xt, qw, ow, cosT, sinT);
    k_gemm_qkv<<<dim3(128, 6), dim3(256), 0, stream>>>(xt, qw, cosT, sinT, qbuf, kbuf, vbuf);
    k_attn<<<dim3(1024), dim3(256), 0, stream>>>(qbuf, kbuf, vbuf, pmsk, aobuf);
    k_gemm_out<<<dim3(128, 4), dim3(256), 0, stream>>>(aobuf, ow, out);
}